// Round 9
// baseline (5023.922 us; speedup 1.0000x reference)
//
#include <hip/hip_runtime.h>

// AdaptiveDownsampling: farthest point sampling (B=8, N=8192, m=4096) + gather.
// Outputs concatenated flat: dp [8,4096,3] then df [8,4096,256], float32.
//
// r2: np reference computes in float64 -> exact path must be fp64.
// r3-r5: register-array spill / AGPR tax lessons; named scalars only.
// r6: fp32 screen + rare exact fp64 path (sound: nonneg terms, margin 1e-4).
// r7: DPP wave max (verified exact). 4239 us; tail = 2 barriers + 2 LDS
//     atomics + 3 dependent LDS reads ~1800 cyc/iter of serial latency.
// r8: single-barrier reduction (compile fix r9: dpp ctrl as template arg).
//     Per-wave (max_bits,first_idx) via DPP; lane0 plain-writes 16B pair
//     (double-buffered); one __syncthreads; every wave redundantly
//     lex-reduces the 16 entries with 4 DPP row_shr stages (exact: max
//     bits, tie -> min idx). Waves with no fp64 update this iter (ballot)
//     skip all reduce work and reuse cached per-wave results (winner's
//     wave is always dirty since its mind -> 0, so the skip is safe).

typedef float v2f __attribute__((ext_vector_type(2)));

#define BATCH 8
#define NPTS  8192
#define MSEL  4096
#define NFEAT 256
#define BLOCK 1024

// fp64 square, opaque to the compiler so no v_fma_f64 contraction can merge
// the following adds (numpy float64 does separate mul / add / add).
__device__ __forceinline__ double sqd(double x) {
    double r;
    asm("v_mul_f64 %0, %1, %1" : "=v"(r) : "v"(x));
    return r;
}

// Exact 64-lane u32 max, VALU-only DPP (r7-verified), broadcast via lane 63.
__device__ __forceinline__ unsigned wave_umax(unsigned v) {
    unsigned t;
    t = (unsigned)__builtin_amdgcn_update_dpp(0, (int)v, 0x111, 0xf, 0xf, false); v = v > t ? v : t; // row_shr:1
    t = (unsigned)__builtin_amdgcn_update_dpp(0, (int)v, 0x112, 0xf, 0xf, false); v = v > t ? v : t; // row_shr:2
    t = (unsigned)__builtin_amdgcn_update_dpp(0, (int)v, 0x114, 0xf, 0xf, false); v = v > t ? v : t; // row_shr:4
    t = (unsigned)__builtin_amdgcn_update_dpp(0, (int)v, 0x118, 0xf, 0xf, false); v = v > t ? v : t; // row_shr:8
    t = (unsigned)__builtin_amdgcn_update_dpp(0, (int)v, 0x142, 0xf, 0xf, false); v = v > t ? v : t; // row_bcast:15
    t = (unsigned)__builtin_amdgcn_update_dpp(0, (int)v, 0x143, 0xf, 0xf, false); v = v > t ? v : t; // row_bcast:31
    return (unsigned)__builtin_amdgcn_readlane((int)v, 63);
}

// Exact 64-lane u32 min, same structure (identity = 0xffffffff for invalids).
__device__ __forceinline__ unsigned wave_umin(unsigned v) {
    unsigned t;
    t = (unsigned)__builtin_amdgcn_update_dpp(-1, (int)v, 0x111, 0xf, 0xf, false); v = v < t ? v : t;
    t = (unsigned)__builtin_amdgcn_update_dpp(-1, (int)v, 0x112, 0xf, 0xf, false); v = v < t ? v : t;
    t = (unsigned)__builtin_amdgcn_update_dpp(-1, (int)v, 0x114, 0xf, 0xf, false); v = v < t ? v : t;
    t = (unsigned)__builtin_amdgcn_update_dpp(-1, (int)v, 0x118, 0xf, 0xf, false); v = v < t ? v : t;
    t = (unsigned)__builtin_amdgcn_update_dpp(-1, (int)v, 0x142, 0xf, 0xf, false); v = v < t ? v : t;
    t = (unsigned)__builtin_amdgcn_update_dpp(-1, (int)v, 0x143, 0xf, 0xf, false); v = v < t ? v : t;
    return (unsigned)__builtin_amdgcn_readlane((int)v, 63);
}

// One lex-reduce stage over rows of 16: candidate = neighbor (hi,lo,idx);
// take if (val greater) or (equal and smaller index). Invalid lanes inject
// (0, 0, 0xffffffff) which always loses to any real entry.
// CTRL is a template arg: __builtin_amdgcn_update_dpp requires an ICE.
template <int CTRL>
__device__ __forceinline__ void lex_stage(unsigned& hi, unsigned& lo, unsigned& idx) {
    const unsigned ohi  = (unsigned)__builtin_amdgcn_update_dpp(0,  (int)hi,  CTRL, 0xf, 0xf, false);
    const unsigned olo  = (unsigned)__builtin_amdgcn_update_dpp(0,  (int)lo,  CTRL, 0xf, 0xf, false);
    const unsigned oidx = (unsigned)__builtin_amdgcn_update_dpp(-1, (int)idx, CTRL, 0xf, 0xf, false);
    const bool take = (ohi > hi) || (ohi == hi && ((olo > lo) || (olo == lo && oidx < idx)));
    hi  = take ? ohi  : hi;
    lo  = take ? olo  : lo;
    idx = take ? oidx : idx;
}

__launch_bounds__(BLOCK, 1)
__global__ void fps_kernel(const float* __restrict__ pts,   // [B, N, 3]
                           float* __restrict__ dp,          // [B, M, 3]
                           int* __restrict__ idx_out)       // [B, M]
{
    __shared__ float s_pts[NPTS * 3];            // 96 KB fp32 copy (winner broadcast)
    __shared__ ulonglong2 s_pair[2][16];         // per-wave {max_bits, idx}, ping-pong

    const int b   = blockIdx.x;
    const int tid = threadIdx.x;
    const float* p = pts + (size_t)b * NPTS * 3;

    for (int i = tid; i < NPTS * 3; i += BLOCK) s_pts[i] = p[i];

    // Coords as float2 pairs (slots 2P, 2P+1) -> packed-fp32 screen.
#define DECLP(P, J0, J1) \
    v2f pxp##P = { p[(tid + J0 * 1024) * 3 + 0], p[(tid + J1 * 1024) * 3 + 0] }; \
    v2f pyp##P = { p[(tid + J0 * 1024) * 3 + 1], p[(tid + J1 * 1024) * 3 + 1] }; \
    v2f pzp##P = { p[(tid + J0 * 1024) * 3 + 2], p[(tid + J1 * 1024) * 3 + 2] };
    DECLP(0, 0, 1) DECLP(1, 2, 3) DECLP(2, 4, 5) DECLP(3, 6, 7)
#undef DECLP
    double mind0 = 1e10, mind1 = 1e10, mind2 = 1e10, mind3 = 1e10;
    double mind4 = 1e10, mind5 = 1e10, mind6 = 1e10, mind7 = 1e10;
    float  mfm0 = 1.0001e10f, mfm1 = 1.0001e10f, mfm2 = 1.0001e10f, mfm3 = 1.0001e10f;
    float  mfm4 = 1.0001e10f, mfm5 = 1.0001e10f, mfm6 = 1.0001e10f, mfm7 = 1.0001e10f;

    // Selection 0 is point 0 (deterministic start).
    float cx = p[0], cy = p[1], cz = p[2];
    if (tid == 0) {
        dp[(size_t)b * MSEL * 3 + 0] = cx;
        dp[(size_t)b * MSEL * 3 + 1] = cy;
        dp[(size_t)b * MSEL * 3 + 2] = cz;
        idx_out[b * MSEL + 0] = 0;
    }

    const int lane = tid & 63;
    const int wid  = tid >> 6;

    // Per-wave cached result (wave-uniform after readlane; recomputed only
    // when some lane's mind changed). k=1 makes every wave dirty.
    unsigned long long wbits = 0ull;
    unsigned           widxw = 0xffffffffu;

    __syncthreads();   // s_pts visible

    for (int k = 1; k < MSEL; ++k) {
        const double cxd = (double)cx, cyd = (double)cy, czd = (double)cz;
        const v2f cx2 = {cx, cx}, cy2 = {cy, cy}, cz2 = {cz, cz};
        bool upd = false;

        // --- packed fp32 screen; exact fp64 update only on trigger ---
#define EX64(PX, PY, PZ, J) { \
        const double ddx = (double)(PX) - cxd; \
        const double ddy = (double)(PY) - cyd; \
        const double ddz = (double)(PZ) - czd; \
        const double dd  = (sqd(ddx) + sqd(ddy)) + sqd(ddz); \
        if (dd < mind##J) { mind##J = dd; mfm##J = (float)dd * 1.0001f; upd = true; } }
#define UPDP(P, J0, J1) { \
        const v2f dx = pxp##P - cx2, dy = pyp##P - cy2, dz = pzp##P - cz2; \
        const v2f d  = dx * dx + dy * dy + dz * dz; \
        if (d.x < mfm##J0) EX64(pxp##P.x, pyp##P.x, pzp##P.x, J0) \
        if (d.y < mfm##J1) EX64(pxp##P.y, pyp##P.y, pzp##P.y, J1) }
        UPDP(0, 0, 1) UPDP(1, 2, 3) UPDP(2, 4, 5) UPDP(3, 6, 7)
#undef UPDP
#undef EX64

        // --- per-wave reduce, only if some lane updated (wave-uniform skip) ---
        if (__ballot(upd) != 0ull) {
            const double a0 = fmax(mind0, mind1), a1 = fmax(mind2, mind3);
            const double a2 = fmax(mind4, mind5), a3 = fmax(mind6, mind7);
            const double tbv = fmax(fmax(a0, a1), fmax(a2, a3));

            // wave max of nonneg double bits: two u32 DPP passes (exact)
            const unsigned long long tb = (unsigned long long)__double_as_longlong(tbv);
            const unsigned thi  = (unsigned)(tb >> 32);
            const unsigned hmax = wave_umax(thi);
            const unsigned lmax = wave_umax((thi == hmax) ? (unsigned)tb : 0u);
            wbits = ((unsigned long long)hmax << 32) | (unsigned long long)lmax;

            // owners publish first matching global index; wave min (exact)
            unsigned n = 0xffffffffu;
            if ((unsigned long long)__double_as_longlong(tbv) == wbits) {
                if (mind7 == tbv) n = (unsigned)(tid + 7 * 1024);
                if (mind6 == tbv) n = (unsigned)(tid + 6 * 1024);
                if (mind5 == tbv) n = (unsigned)(tid + 5 * 1024);
                if (mind4 == tbv) n = (unsigned)(tid + 4 * 1024);
                if (mind3 == tbv) n = (unsigned)(tid + 3 * 1024);
                if (mind2 == tbv) n = (unsigned)(tid + 2 * 1024);
                if (mind1 == tbv) n = (unsigned)(tid + 1 * 1024);
                if (mind0 == tbv) n = (unsigned)tid;
            }
            widxw = wave_umin(n);
        }
        if (lane == 0)
            s_pair[k & 1][wid] = (ulonglong2){wbits, (unsigned long long)widxw};
        __syncthreads();                                   // the ONLY barrier

        // --- redundant per-wave final reduce of the 16 pairs (DPP lex) ---
        const ulonglong2 e = s_pair[k & 1][lane & 15];
        unsigned hi  = (unsigned)(e.x >> 32);
        unsigned lo  = (unsigned)e.x;
        unsigned idx = (unsigned)e.y;
        lex_stage<0x111>(hi, lo, idx);   // row_shr:1
        lex_stage<0x112>(hi, lo, idx);   // row_shr:2
        lex_stage<0x114>(hi, lo, idx);   // row_shr:4
        lex_stage<0x118>(hi, lo, idx);   // row_shr:8  -> lane 15 of each row
        const int widx = __builtin_amdgcn_readlane((int)idx, 15);

        // --- broadcast winner coords from LDS (same-addr = conflict-free) ---
        const float wx = s_pts[widx * 3 + 0];
        const float wy = s_pts[widx * 3 + 1];
        const float wz = s_pts[widx * 3 + 2];
        if (tid == 0) {
            idx_out[b * MSEL + k] = widx;
            float* o = dp + ((size_t)b * MSEL + k) * 3;
            o[0] = wx; o[1] = wy; o[2] = wz;
        }
        cx = wx; cy = wy; cz = wz;
    }
}

// One wave per selected row; lane i moves one float4 (64 * 16B = 1024B = full row).
__global__ void gather_kernel(const float* __restrict__ feats,  // [B, N, C]
                              const int* __restrict__ idx,      // [B, M]
                              float* __restrict__ df)           // [B, M, C]
{
    const int row  = blockIdx.x * 4 + (threadIdx.x >> 6);  // [0, B*M)
    const int lane = threadIdx.x & 63;
    const int b    = row >> 12;         // MSEL = 4096 rows per batch
    const int src  = idx[row];
    const float4* s = (const float4*)(feats + ((size_t)b * NPTS + src) * NFEAT);
    float4*       d = (float4*)(df + (size_t)row * NFEAT);
    d[lane] = s[lane];
}

extern "C" void kernel_launch(void* const* d_in, const int* in_sizes, int n_in,
                              void* d_out, int out_size, void* d_ws, size_t ws_size,
                              hipStream_t stream)
{
    const float* points   = (const float*)d_in[0];   // [8, 8192, 3]
    const float* features = (const float*)d_in[1];   // [8, 8192, 256]
    float* out = (float*)d_out;
    float* dp  = out;                                // [8, 4096, 3]
    float* df  = out + (size_t)BATCH * MSEL * 3;     // [8, 4096, 256]
    int*   idx_ws = (int*)d_ws;                      // [8, 4096] = 128 KB scratch

    fps_kernel<<<BATCH, BLOCK, 0, stream>>>(points, dp, idx_ws);
    gather_kernel<<<(BATCH * MSEL) / 4, 256, 0, stream>>>(features, idx_ws, df);
}